// Round 11
// baseline (200.410 us; speedup 1.0000x reference)
//
#include <hip/hip_runtime.h>
#include <hip/hip_bf16.h>
#include <hip/hip_cooperative_groups.h>
#include <math.h>

// ---------------------------------------------------------------------------
// BernNet: out = log_softmax( bern_prop( relu(x@W1+b1)@W2+b2 ) )
// bern_prop in monomial basis (10 matvecs, not 65); trailing-zero fast path:
// graph work in ONE cooperative kernel that exits when a_j==0 for j>=1
// (log_softmax then fused into the MLP epilogue).
// MLP phase-1: LDS-free K-loop. A (x fp32) direct global->VGPR with depth-2
// triple-buffer; B (W1, fragment-linear bf16, L2-resident) depth-1 double-
// buffer. One sched_barrier(0) per unrolled iteration pins [loads][compute]
// so the scheduler cannot sink the prefetch (R9's failure: VGPR=52 proved
// the dbuf was dissolved). x->bf16 by truncation (1 op / 2 floats).
// h1 through a 64KB frag-linear LDS image (one barrier); phase-2 h1@W2 with
// split hi/lo bf16 W2; fused log_softmax epilogue on the fast path.
// ---------------------------------------------------------------------------

#define KORD 10

namespace cg = cooperative_groups;

typedef __attribute__((ext_vector_type(8))) short bf16x8;
typedef __attribute__((ext_vector_type(4))) float f32x4;

static __device__ __forceinline__ ushort f2bf(float f) {   // RNE
    unsigned u = __float_as_uint(f);
    unsigned r = (u + 0x7fffu + ((u >> 16) & 1u)) >> 16;
    return (ushort)r;
}
static __device__ __forceinline__ float bf2f(ushort h) {
    return __uint_as_float(((unsigned)h) << 16);
}
// truncation pack: low16 = bf16_trunc(a), high16 = bf16_trunc(b)
static __device__ __forceinline__ uint pk2t(float a, float b) {
    return (__float_as_uint(a) >> 16) | (__float_as_uint(b) & 0xffff0000u);
}
static __device__ __forceinline__ bf16x8 mk8(uint a, uint b, uint c, uint d) {
    union { uint4 u; bf16x8 v; } x;
    x.u = make_uint4(a, b, c, d);
    return x.v;
}

// ---- one-time setup: monomial coeffs + weight conversion -------------------
// W1 -> fragment-linear bf16: idx = kt*8192 + col*32 + lg*8 + j  (k=kt*32+lg*8+j)
// W2 -> hi/lo bf16:           idx = ks*2048 + col*32 + lg*8 + j  (k=ks*32+lg*8+j)
__global__ void prep_all(const float* __restrict__ temp,
                         const float* __restrict__ W1, const float* __restrict__ W2,
                         float* __restrict__ acoef, int* __restrict__ flags,
                         ushort* __restrict__ w1b,
                         ushort* __restrict__ w2h, ushort* __restrict__ w2l)
{
    int tid = blockIdx.x * 256 + threadIdx.x;
    if (tid == 0) {
        int C[KORD + 1][KORD + 1];
        for (int n = 0; n <= KORD; ++n) {
            for (int k = 0; k <= KORD; ++k) C[n][k] = 0;
            C[n][0] = 1;
            for (int k = 1; k <= n; ++k)
                C[n][k] = C[n - 1][k - 1] + ((k <= n - 1) ? C[n - 1][k] : 0);
        }
        float a[KORD + 1];
        for (int j = 0; j <= KORD; ++j) a[j] = 0.f;
        for (int m = 0; m <= KORD; ++m) {
            float tm = temp[m];
            tm = tm > 0.f ? tm : 0.f;
            float cm = (float)C[KORD][m] / 1024.0f;
            for (int p = 0; p <= m; ++p)
                for (int q = 0; q <= KORD - m; ++q) {
                    int Mij = ((p & 1) ? -1 : 1) * C[m][p] * C[KORD - m][q];
                    a[p + q] += cm * tm * (float)Mij;
                }
        }
        for (int j = 0; j <= KORD; ++j) acoef[j] = a[j];
        int any = 0;
        for (int j = KORD; j >= 0; --j) {
            if (a[j] != 0.f) any = 1;
            flags[j] = any;
        }
    }
    if (tid < 512 * 256) {
        int j = tid & 7, lg = (tid >> 3) & 3, col = (tid >> 5) & 255, kt = tid >> 13;
        int k = kt * 32 + lg * 8 + j;
        w1b[tid] = f2bf(W1[k * 256 + col]);
    } else if (tid < 512 * 256 + 256 * 64) {
        int t2 = tid - 512 * 256;
        int j = t2 & 7, lg = (t2 >> 3) & 3, col = (t2 >> 5) & 63, ks = t2 >> 11;
        int k = ks * 32 + lg * 8 + j;
        float v = W2[k * 64 + col];
        ushort hi = f2bf(v);
        ushort lo = f2bf(v - bf2f(hi));
        w2h[t2] = hi; w2l[t2] = lo;
    }
}

// ---- fused MLP ------------------------------------------------------------
// 512 thr / 8 waves; tile 128 rows x 256 cols, K=512.
// Phase 1: wave wid -> rows (wid>>1)*32..+31, cols (wid&1)*128..+127.
//   Per kt: 4 A loads (fp32, kt+2) + 8 B loads (bf16 frag, kt+1), fence,
//   2 cvt-packs + 16 MFMA. No LDS, no barriers in the loop.
// Exchange: h1 bf16 frag-linear image (64KB), ONE barrier.
// Phase 2: 8 waves, rows wid*16..+15, 64 cols, K=256.
__global__ __launch_bounds__(512, 2) void mlp_kernel(
    const float* __restrict__ x,
    const ushort* __restrict__ w1b,
    const ushort* __restrict__ w2h, const ushort* __restrict__ w2l,
    const float* __restrict__ b1, const float* __restrict__ b2,
    float* __restrict__ v0, float* __restrict__ out,
    const float* __restrict__ acoef, const int* __restrict__ flags, int N)
{
    __shared__ __align__(16) ushort h1l[128 * 256];    // 64KB frag-linear image

    const int t    = threadIdx.x;
    const int lane = t & 63;
    const int wid  = t >> 6;        // 0..7
    const int rs   = wid >> 1;      // 0..3 (32-row slab)
    const int cs   = wid & 1;       // 0..1 (128-col half)
    const int l15  = lane & 15;
    const int lg   = lane >> 4;
    const int row0 = blockIdx.x * 128;

    // A row pointers (2 row-frags), clamped (no OOB; epilogue guards stores)
    int r0 = row0 + rs * 32 + l15;      if (r0 > N - 1) r0 = N - 1;
    int r1 = row0 + rs * 32 + 16 + l15; if (r1 > N - 1) r1 = N - 1;
    const float* ap0 = x + (size_t)r0 * 512 + lg * 8;
    const float* ap1 = x + (size_t)r1 * 512 + lg * 8;
    const ushort* bp = w1b + (cs * 128 + l15) * 32 + lg * 8;

    f32x4 acc[2][8];
#pragma unroll
    for (int i = 0; i < 2; ++i)
#pragma unroll
        for (int j = 0; j < 8; ++j) acc[i][j] = (f32x4)0.f;

    float4 A0b[3][2], A1b[3][2];    // [buf][rowfrag]: first/second 16B of 32B
    bf16x8 Bb[2][8];

    // ---- prologue: A kt=0,1 ; B kt=0 ----
#pragma unroll
    for (int p = 0; p < 2; ++p) {
        A0b[p][0] = *(const float4*)(ap0 + p * 32);
        A1b[p][0] = *(const float4*)(ap0 + p * 32 + 4);
        A0b[p][1] = *(const float4*)(ap1 + p * 32);
        A1b[p][1] = *(const float4*)(ap1 + p * 32 + 4);
    }
#pragma unroll
    for (int cf = 0; cf < 8; ++cf)
        Bb[0][cf] = *(const bf16x8*)(bp + cf * 512);
    __builtin_amdgcn_sched_barrier(0);

#pragma unroll
    for (int kt = 0; kt < 16; ++kt) {
        // issue next loads (A depth-2, B depth-1) — pinned above the fence
        if (kt + 2 < 16) {
            A0b[(kt + 2) % 3][0] = *(const float4*)(ap0 + (kt + 2) * 32);
            A1b[(kt + 2) % 3][0] = *(const float4*)(ap0 + (kt + 2) * 32 + 4);
            A0b[(kt + 2) % 3][1] = *(const float4*)(ap1 + (kt + 2) * 32);
            A1b[(kt + 2) % 3][1] = *(const float4*)(ap1 + (kt + 2) * 32 + 4);
        }
        if (kt + 1 < 16) {
#pragma unroll
            for (int cf = 0; cf < 8; ++cf)
                Bb[(kt + 1) & 1][cf] =
                    *(const bf16x8*)(bp + (kt + 1) * 8192 + cf * 512);
        }
        __builtin_amdgcn_sched_barrier(0);
        // convert current A (truncation: 1 op / 2 floats)
        float4 f00 = A0b[kt % 3][0], f01 = A1b[kt % 3][0];
        float4 f10 = A0b[kt % 3][1], f11 = A1b[kt % 3][1];
        bf16x8 Af0 = mk8(pk2t(f00.x, f00.y), pk2t(f00.z, f00.w),
                         pk2t(f01.x, f01.y), pk2t(f01.z, f01.w));
        bf16x8 Af1 = mk8(pk2t(f10.x, f10.y), pk2t(f10.z, f10.w),
                         pk2t(f11.x, f11.y), pk2t(f11.z, f11.w));
#pragma unroll
        for (int cf = 0; cf < 8; ++cf) {
            acc[0][cf] = __builtin_amdgcn_mfma_f32_16x16x32_bf16(Af0, Bb[kt & 1][cf], acc[0][cf], 0, 0, 0);
            acc[1][cf] = __builtin_amdgcn_mfma_f32_16x16x32_bf16(Af1, Bb[kt & 1][cf], acc[1][cf], 0, 0, 0);
        }
    }

    // ---- h1 = relu(acc+b1) -> bf16 -> LDS frag-linear image ----
    // element (row,col): g=row>>4, idx = ((ks*8+g)*64 + (row&15)*4 + lgw)*8 + j
#pragma unroll
    for (int cf = 0; cf < 8; ++cf) {
        int col = cs * 128 + cf * 16 + l15;
        float bb = b1[col];
        int ks = col >> 5, lgw = (col >> 3) & 3, j = col & 7;
#pragma unroll
        for (int rg = 0; rg < 2; ++rg) {
            int g = rs * 2 + rg;
#pragma unroll
            for (int r = 0; r < 4; ++r) {
                float v = fmaxf(acc[rg][cf][r] + bb, 0.f);
                int rowin = lg * 4 + r;                 // row & 15
                h1l[((ks * 8 + g) * 64 + rowin * 4 + lgw) * 8 + j] = f2bf(v);
            }
        }
    }
    __syncthreads();

    // ---- phase 2: wave wid -> rows wid*16..+15, all 64 cols, K=256 ----
    f32x4 acc2[4];
#pragma unroll
    for (int i = 0; i < 4; ++i) acc2[i] = (f32x4)0.f;
#pragma unroll
    for (int ks = 0; ks < 8; ++ks) {
        bf16x8 A = *(const bf16x8*)&h1l[((ks * 8 + wid) * 64 + l15 * 4 + lg) * 8];
#pragma unroll
        for (int nf = 0; nf < 4; ++nf) {
            size_t bo = (size_t)ks * 2048 + (nf * 16 + l15) * 32 + (lg << 3);
            bf16x8 Bh = *(const bf16x8*)(w2h + bo);
            bf16x8 Bl = *(const bf16x8*)(w2l + bo);
            acc2[nf] = __builtin_amdgcn_mfma_f32_16x16x32_bf16(A, Bh, acc2[nf], 0, 0, 0);
            acc2[nf] = __builtin_amdgcn_mfma_f32_16x16x32_bf16(A, Bl, acc2[nf], 0, 0, 0);
        }
    }

    // ---- epilogue ----
    int flag1 = flags[1];
    float a0c = acoef[0];
    float z[4][4];
#pragma unroll
    for (int nf = 0; nf < 4; ++nf) {
        float bb = b2[nf * 16 + l15];
#pragma unroll
        for (int r = 0; r < 4; ++r) z[nf][r] = acc2[nf][r] + bb;
    }
    if (!flag1) {
        // fused log_softmax: the 16 l15-lanes of this lg group share 4 rows
#pragma unroll
        for (int r = 0; r < 4; ++r) {
            int row = row0 + wid * 16 + lg * 4 + r;
            float mx = fmaxf(fmaxf(z[0][r], z[1][r]), fmaxf(z[2][r], z[3][r]));
#pragma unroll
            for (int off = 1; off < 16; off <<= 1) mx = fmaxf(mx, __shfl_xor(mx, off, 64));
            float s = expf(z[0][r] - mx) + expf(z[1][r] - mx)
                    + expf(z[2][r] - mx) + expf(z[3][r] - mx);
#pragma unroll
            for (int off = 1; off < 16; off <<= 1) s += __shfl_xor(s, off, 64);
            float lns = logf(s);
            if (row < N) {
#pragma unroll
                for (int nf = 0; nf < 4; ++nf)
                    out[(size_t)row * 64 + nf * 16 + l15] = z[nf][r] - mx - lns;
            }
        }
    } else {
#pragma unroll
        for (int nf = 0; nf < 4; ++nf) {
            int col = nf * 16 + l15;
#pragma unroll
            for (int r = 0; r < 4; ++r) {
                int row = row0 + wid * 16 + lg * 4 + r;
                if (row < N) {
                    size_t o = (size_t)row * 64 + col;
                    v0[o] = z[nf][r];
                    out[o] = a0c * z[nf][r];
                }
            }
        }
    }
}

// ---- all graph work in one cooperative kernel (active path only) ----------
__global__ __launch_bounds__(256) void graph_coop(
    const int* __restrict__ src, const int* __restrict__ dst, int E, int N,
    int* __restrict__ degs, int* __restrict__ degd, int* __restrict__ cursor,
    int* __restrict__ rowp, int* __restrict__ csrs, float* __restrict__ csrw,
    float* __restrict__ v0, float* __restrict__ v1, float* __restrict__ out,
    const float* __restrict__ acoef, const int* __restrict__ flags)
{
    __shared__ int sums[256];
    if (!flags[1]) return;                  // uniform early-out: no syncs occur
    cg::grid_group grid = cg::this_grid();
    int gtid = blockIdx.x * 256 + threadIdx.x;
    int gstr = gridDim.x * 256;

    for (int i = gtid; i < N; i += gstr) { degs[i] = 0; degd[i] = 0; cursor[i] = 0; }
    grid.sync();
    for (int e = gtid; e < E; e += gstr) {
        atomicAdd(&degs[src[e]], 1);
        atomicAdd(&degd[dst[e]], 1);
    }
    grid.sync();
    if (blockIdx.x == 0) {
        int tid = threadIdx.x;
        int chunk = (N + 255) / 256;
        int s0 = tid * chunk;
        int s1 = s0 + chunk; if (s1 > N) s1 = N; if (s0 > N) s0 = N;
        int s = 0;
        for (int i = s0; i < s1; ++i) s += degd[i];
        sums[tid] = s;
        __syncthreads();
        for (int off = 1; off < 256; off <<= 1) {
            int v = (tid >= off) ? sums[tid - off] : 0;
            __syncthreads();
            sums[tid] += v;
            __syncthreads();
        }
        int run = sums[tid] - s;
        for (int i = s0; i < s1; ++i) { rowp[i] = run; run += degd[i]; }
        if (tid == 255) rowp[N] = sums[255];
    }
    grid.sync();
    for (int e = gtid; e < E; e += gstr) {
        int s = src[e], d = dst[e];
        int dgs = degs[s], dgd = degs[d];
        float ws_ = (dgs > 0 ? rsqrtf((float)dgs) : 0.f)
                  * (dgd > 0 ? rsqrtf((float)dgd) : 0.f);
        int slot = rowp[d] + atomicAdd(&cursor[d], 1);
        csrs[slot] = s;
        csrw[slot] = ws_;
    }
    grid.sync();
    const float* va = v0;
    float* vb = v1;
    int lane = threadIdx.x & 63;
    int grpbase = lane & 48;
    for (int j = 1; j <= KORD; ++j) {
        if (!flags[j]) break;               // uniform
        float aj = acoef[j];
        for (int idx = gtid; idx < N * 16; idx += gstr) {
            int n = idx >> 4;
            int q = idx & 15;
            int beg = rowp[n], end = rowp[n + 1];
            float4 acc = make_float4(0.f, 0.f, 0.f, 0.f);
            for (int base = beg; base < end; base += 16) {
                int s = 0; float wvv = 0.f;
                int ii = base + q;
                if (ii < end) { s = csrs[ii]; wvv = csrw[ii]; }
                int m = end - base; if (m > 16) m = 16;
                for (int u = 0; u < m; ++u) {
                    int ss = __shfl(s, grpbase + u, 64);
                    float ww = __shfl(wvv, grpbase + u, 64);
                    float4 vv = *(const float4*)(va + ((long)ss << 6) + (q << 2));
                    acc.x += ww * vv.x; acc.y += ww * vv.y;
                    acc.z += ww * vv.z; acc.w += ww * vv.w;
                }
            }
            long o = ((long)n << 6) + (q << 2);
            *(float4*)(vb + o) = acc;
            float4 ov = *(const float4*)(out + o);
            ov.x += aj * acc.x; ov.y += aj * acc.y;
            ov.z += aj * acc.z; ov.w += aj * acc.w;
            *(float4*)(out + o) = ov;
        }
        grid.sync();
        float* tsw = vb; vb = (float*)va; va = tsw;
    }
    for (int idx = gtid; idx < N * 64; idx += gstr) {
        int n = idx >> 6;
        int c = idx & 63;
        float v = out[(long)n * 64 + c];
        float mx = v;
#pragma unroll
        for (int off = 32; off; off >>= 1) mx = fmaxf(mx, __shfl_xor(mx, off, 64));
        float e = expf(v - mx);
        float s = e;
#pragma unroll
        for (int off = 32; off; off >>= 1) s += __shfl_xor(s, off, 64);
        out[(long)n * 64 + c] = v - mx - logf(s);
    }
}

extern "C" void kernel_launch(void* const* d_in, const int* in_sizes, int n_in,
                              void* d_out, int out_size, void* d_ws, size_t ws_size,
                              hipStream_t stream)
{
    const float* x    = (const float*)d_in[0];
    const int*   ei   = (const int*)d_in[1];
    const float* W1   = (const float*)d_in[2];
    const float* b1   = (const float*)d_in[3];
    const float* W2   = (const float*)d_in[4];
    const float* b2   = (const float*)d_in[5];
    const float* temp = (const float*)d_in[6];

    int N = in_sizes[0] / 512;
    int E = in_sizes[1] / 2;
    const int* src = ei;
    const int* dst = ei + E;
    float* out = (float*)d_out;

    char* w = (char*)d_ws;
    auto alloc = [&](size_t bytes) {
        char* p = w;
        w += (bytes + 255) & ~(size_t)255;
        return p;
    };
    float* acoef  = (float*)alloc(64);
    int*   flags  = (int*)alloc(64);
    int*   degs   = (int*)alloc((size_t)N * 4);
    int*   degd   = (int*)alloc((size_t)N * 4);
    int*   cursor = (int*)alloc((size_t)N * 4);
    int*   rowp   = (int*)alloc((size_t)(N + 1) * 4);
    int*   csrs   = (int*)alloc((size_t)E * 4);
    float* csrw   = (float*)alloc((size_t)E * 4);
    ushort* w1b   = (ushort*)alloc(512 * 256 * 2);
    ushort* w2h   = (ushort*)alloc(256 * 64 * 2);
    ushort* w2l   = (ushort*)alloc(256 * 64 * 2);
    float* v0     = (float*)alloc((size_t)N * 64 * 4);
    float* v1     = (float*)alloc((size_t)N * 64 * 4);

    prep_all<<<576, 256, 0, stream>>>(temp, W1, W2, acoef, flags, w1b, w2h, w2l);

    int ntiles = (N + 127) / 128;
    mlp_kernel<<<ntiles, 512, 0, stream>>>(x, w1b, w2h, w2l, b1, b2, v0, out,
                                           acoef, flags, N);

    int Ei = E, Ni = N;
    void* cargs[] = {
        (void*)&src, (void*)&dst, (void*)&Ei, (void*)&Ni,
        (void*)&degs, (void*)&degd, (void*)&cursor, (void*)&rowp,
        (void*)&csrs, (void*)&csrw, (void*)&v0, (void*)&v1, (void*)&out,
        (void*)&acoef, (void*)&flags
    };
    hipLaunchCooperativeKernel((void*)graph_coop, dim3(1024), dim3(256),
                               cargs, 0, stream);
}

// Round 12
// 193.520 us; speedup vs baseline: 1.0356x; 1.0356x over previous
//
#include <hip/hip_runtime.h>
#include <hip/hip_bf16.h>
#include <hip/hip_cooperative_groups.h>
#include <math.h>

// ---------------------------------------------------------------------------
// BernNet: out = log_softmax( bern_prop( relu(x@W1+b1)@W2+b2 ) )
// bern_prop in monomial basis (10 matvecs, not 65); trailing-zero fast path:
// graph work in ONE cooperative kernel that exits when a_j==0 for j>=1
// (log_softmax then fused into the MLP epilogue).
// MLP: pure-TLP phase-1. Tile 32 rows x 256 cols, 4 waves, NO barriers and
// NO LDS in the K-loop: each wave owns 64 cols (B unique, L2-hot
// fragment-linear w1b), reads the shared 32-row x slab directly (L1 absorbs
// the 4x reuse; HBM-unique bytes = x once). ~20 waves/CU each with 12
// independent loads/iter = deep chip-wide memory parallelism -> HBM-bound,
// no software pipelining to fight the compiler over.
// h1 via 16KB conflict-free LDS image (one barrier); phase-2 h1@W2 with
// split hi/lo bf16 W2; fused log_softmax epilogue on the fast path.
// ---------------------------------------------------------------------------

#define KORD 10

namespace cg = cooperative_groups;

typedef __attribute__((ext_vector_type(8))) short bf16x8;
typedef __attribute__((ext_vector_type(4))) float f32x4;

static __device__ __forceinline__ ushort f2bf(float f) {   // RNE
    unsigned u = __float_as_uint(f);
    unsigned r = (u + 0x7fffu + ((u >> 16) & 1u)) >> 16;
    return (ushort)r;
}
static __device__ __forceinline__ float bf2f(ushort h) {
    return __uint_as_float(((unsigned)h) << 16);
}
// truncation pack: low16 = bf16_trunc(a), high16 = bf16_trunc(b)
static __device__ __forceinline__ uint pk2t(float a, float b) {
    return (__float_as_uint(a) >> 16) | (__float_as_uint(b) & 0xffff0000u);
}
static __device__ __forceinline__ bf16x8 mk8(uint a, uint b, uint c, uint d) {
    union { uint4 u; bf16x8 v; } x;
    x.u = make_uint4(a, b, c, d);
    return x.v;
}

// ---- one-time setup: monomial coeffs + weight conversion -------------------
// W1 -> fragment-linear bf16: idx = kt*8192 + col*32 + lg*8 + j  (k=kt*32+lg*8+j)
// W2 -> hi/lo bf16:           idx = ks*2048 + col*32 + lg*8 + j  (k=ks*32+lg*8+j)
__global__ void prep_all(const float* __restrict__ temp,
                         const float* __restrict__ W1, const float* __restrict__ W2,
                         float* __restrict__ acoef, int* __restrict__ flags,
                         ushort* __restrict__ w1b,
                         ushort* __restrict__ w2h, ushort* __restrict__ w2l)
{
    int tid = blockIdx.x * 256 + threadIdx.x;
    if (tid == 0) {
        int C[KORD + 1][KORD + 1];
        for (int n = 0; n <= KORD; ++n) {
            for (int k = 0; k <= KORD; ++k) C[n][k] = 0;
            C[n][0] = 1;
            for (int k = 1; k <= n; ++k)
                C[n][k] = C[n - 1][k - 1] + ((k <= n - 1) ? C[n - 1][k] : 0);
        }
        float a[KORD + 1];
        for (int j = 0; j <= KORD; ++j) a[j] = 0.f;
        for (int m = 0; m <= KORD; ++m) {
            float tm = temp[m];
            tm = tm > 0.f ? tm : 0.f;
            float cm = (float)C[KORD][m] / 1024.0f;
            for (int p = 0; p <= m; ++p)
                for (int q = 0; q <= KORD - m; ++q) {
                    int Mij = ((p & 1) ? -1 : 1) * C[m][p] * C[KORD - m][q];
                    a[p + q] += cm * tm * (float)Mij;
                }
        }
        for (int j = 0; j <= KORD; ++j) acoef[j] = a[j];
        int any = 0;
        for (int j = KORD; j >= 0; --j) {
            if (a[j] != 0.f) any = 1;
            flags[j] = any;
        }
    }
    if (tid < 512 * 256) {
        int j = tid & 7, lg = (tid >> 3) & 3, col = (tid >> 5) & 255, kt = tid >> 13;
        int k = kt * 32 + lg * 8 + j;
        w1b[tid] = f2bf(W1[k * 256 + col]);
    } else if (tid < 512 * 256 + 256 * 64) {
        int t2 = tid - 512 * 256;
        int j = t2 & 7, lg = (t2 >> 3) & 3, col = (t2 >> 5) & 63, ks = t2 >> 11;
        int k = ks * 32 + lg * 8 + j;
        float v = W2[k * 64 + col];
        ushort hi = f2bf(v);
        ushort lo = f2bf(v - bf2f(hi));
        w2h[t2] = hi; w2l[t2] = lo;
    }
}

// ---- fused MLP ------------------------------------------------------------
// 256 thr / 4 waves; tile 32 rows x 256 cols, K=512.
// Phase 1: wave wv -> ALL 32 rows x cols wv*64..+63. A (x fp32) and B (W1
// bf16 frags) loaded directly; no LDS, no barriers, plain loop -> TLP.
// Exchange: h1 bf16 frag-linear image (16KB), ONE barrier.
// Phase 2: waves 0-1, rows wv*16..+15, 64 cols, K=256.
__global__ __launch_bounds__(256, 4) void mlp_kernel(
    const float* __restrict__ x,
    const ushort* __restrict__ w1b,
    const ushort* __restrict__ w2h, const ushort* __restrict__ w2l,
    const float* __restrict__ b1, const float* __restrict__ b2,
    float* __restrict__ v0, float* __restrict__ out,
    const float* __restrict__ acoef, const int* __restrict__ flags, int N)
{
    __shared__ __align__(16) ushort h1l[32 * 256];     // 16KB frag-linear image

    const int t    = threadIdx.x;
    const int lane = t & 63;
    const int wv   = t >> 6;        // 0..3
    const int l15  = lane & 15;
    const int lg   = lane >> 4;
    const int row0 = blockIdx.x * 32;

    // A row pointers (2 row-frags), clamped (no OOB; stores are guarded)
    int r0 = row0 + l15;      if (r0 > N - 1) r0 = N - 1;
    int r1 = row0 + 16 + l15; if (r1 > N - 1) r1 = N - 1;
    const float* ap0 = x + (size_t)r0 * 512 + lg * 8;
    const float* ap1 = x + (size_t)r1 * 512 + lg * 8;
    const ushort* bp = w1b + (wv * 64 + l15) * 32 + lg * 8;

    f32x4 acc[2][4];
#pragma unroll
    for (int g = 0; g < 2; ++g)
#pragma unroll
        for (int c = 0; c < 4; ++c) acc[g][c] = (f32x4)0.f;

#pragma unroll 2
    for (int kt = 0; kt < 16; ++kt) {
        float4 a00 = *(const float4*)(ap0 + kt * 32);
        float4 a01 = *(const float4*)(ap0 + kt * 32 + 4);
        float4 a10 = *(const float4*)(ap1 + kt * 32);
        float4 a11 = *(const float4*)(ap1 + kt * 32 + 4);
        const ushort* bk = bp + kt * 8192;
        bf16x8 B0 = *(const bf16x8*)(bk);
        bf16x8 B1 = *(const bf16x8*)(bk + 512);
        bf16x8 B2 = *(const bf16x8*)(bk + 1024);
        bf16x8 B3 = *(const bf16x8*)(bk + 1536);
        bf16x8 A0 = mk8(pk2t(a00.x, a00.y), pk2t(a00.z, a00.w),
                        pk2t(a01.x, a01.y), pk2t(a01.z, a01.w));
        bf16x8 A1 = mk8(pk2t(a10.x, a10.y), pk2t(a10.z, a10.w),
                        pk2t(a11.x, a11.y), pk2t(a11.z, a11.w));
        acc[0][0] = __builtin_amdgcn_mfma_f32_16x16x32_bf16(A0, B0, acc[0][0], 0, 0, 0);
        acc[0][1] = __builtin_amdgcn_mfma_f32_16x16x32_bf16(A0, B1, acc[0][1], 0, 0, 0);
        acc[0][2] = __builtin_amdgcn_mfma_f32_16x16x32_bf16(A0, B2, acc[0][2], 0, 0, 0);
        acc[0][3] = __builtin_amdgcn_mfma_f32_16x16x32_bf16(A0, B3, acc[0][3], 0, 0, 0);
        acc[1][0] = __builtin_amdgcn_mfma_f32_16x16x32_bf16(A1, B0, acc[1][0], 0, 0, 0);
        acc[1][1] = __builtin_amdgcn_mfma_f32_16x16x32_bf16(A1, B1, acc[1][1], 0, 0, 0);
        acc[1][2] = __builtin_amdgcn_mfma_f32_16x16x32_bf16(A1, B2, acc[1][2], 0, 0, 0);
        acc[1][3] = __builtin_amdgcn_mfma_f32_16x16x32_bf16(A1, B3, acc[1][3], 0, 0, 0);
    }

    // ---- h1 = relu(acc+b1) -> bf16 -> LDS frag-linear image ----
    // element (row,col): g=row>>4, idx = ((ks*2+g)*64 + (row&15)*4 + lgw)*8 + j
#pragma unroll
    for (int cf = 0; cf < 4; ++cf) {
        int col = wv * 64 + cf * 16 + l15;
        float bb = b1[col];
        int ks = col >> 5, lgw = (col >> 3) & 3, j = col & 7;
#pragma unroll
        for (int g = 0; g < 2; ++g) {
#pragma unroll
            for (int r = 0; r < 4; ++r) {
                float v = fmaxf(acc[g][cf][r] + bb, 0.f);
                h1l[((ks * 2 + g) * 64 + (lg * 4 + r) * 4 + lgw) * 8 + j] = f2bf(v);
            }
        }
    }
    __syncthreads();

    if (wv >= 2) return;                               // no barriers below

    // ---- phase 2: wave wv -> rows wv*16..+15, all 64 cols, K=256 ----
    f32x4 acc2[4];
#pragma unroll
    for (int i = 0; i < 4; ++i) acc2[i] = (f32x4)0.f;
#pragma unroll
    for (int ks = 0; ks < 8; ++ks) {
        bf16x8 A = *(const bf16x8*)&h1l[((ks * 2 + wv) * 64 + l15 * 4 + lg) * 8];
#pragma unroll
        for (int nf = 0; nf < 4; ++nf) {
            size_t bo = (size_t)ks * 2048 + (nf * 16 + l15) * 32 + (lg << 3);
            bf16x8 Bh = *(const bf16x8*)(w2h + bo);
            bf16x8 Bl = *(const bf16x8*)(w2l + bo);
            acc2[nf] = __builtin_amdgcn_mfma_f32_16x16x32_bf16(A, Bh, acc2[nf], 0, 0, 0);
            acc2[nf] = __builtin_amdgcn_mfma_f32_16x16x32_bf16(A, Bl, acc2[nf], 0, 0, 0);
        }
    }

    // ---- epilogue ----
    int flag1 = flags[1];
    float a0c = acoef[0];
    float z[4][4];
#pragma unroll
    for (int nf = 0; nf < 4; ++nf) {
        float bb = b2[nf * 16 + l15];
#pragma unroll
        for (int r = 0; r < 4; ++r) z[nf][r] = acc2[nf][r] + bb;
    }
    if (!flag1) {
        // fused log_softmax: the 16 l15-lanes of this lg group share 4 rows
#pragma unroll
        for (int r = 0; r < 4; ++r) {
            int row = row0 + wv * 16 + lg * 4 + r;
            float mx = fmaxf(fmaxf(z[0][r], z[1][r]), fmaxf(z[2][r], z[3][r]));
#pragma unroll
            for (int off = 1; off < 16; off <<= 1) mx = fmaxf(mx, __shfl_xor(mx, off, 64));
            float s = expf(z[0][r] - mx) + expf(z[1][r] - mx)
                    + expf(z[2][r] - mx) + expf(z[3][r] - mx);
#pragma unroll
            for (int off = 1; off < 16; off <<= 1) s += __shfl_xor(s, off, 64);
            float lns = logf(s);
            if (row < N) {
#pragma unroll
                for (int nf = 0; nf < 4; ++nf)
                    out[(size_t)row * 64 + nf * 16 + l15] = z[nf][r] - mx - lns;
            }
        }
    } else {
#pragma unroll
        for (int nf = 0; nf < 4; ++nf) {
            int col = nf * 16 + l15;
#pragma unroll
            for (int r = 0; r < 4; ++r) {
                int row = row0 + wv * 16 + lg * 4 + r;
                if (row < N) {
                    size_t o = (size_t)row * 64 + col;
                    v0[o] = z[nf][r];
                    out[o] = a0c * z[nf][r];
                }
            }
        }
    }
}

// ---- all graph work in one cooperative kernel (active path only) ----------
__global__ __launch_bounds__(256) void graph_coop(
    const int* __restrict__ src, const int* __restrict__ dst, int E, int N,
    int* __restrict__ degs, int* __restrict__ degd, int* __restrict__ cursor,
    int* __restrict__ rowp, int* __restrict__ csrs, float* __restrict__ csrw,
    float* __restrict__ v0, float* __restrict__ v1, float* __restrict__ out,
    const float* __restrict__ acoef, const int* __restrict__ flags)
{
    __shared__ int sums[256];
    if (!flags[1]) return;                  // uniform early-out: no syncs occur
    cg::grid_group grid = cg::this_grid();
    int gtid = blockIdx.x * 256 + threadIdx.x;
    int gstr = gridDim.x * 256;

    for (int i = gtid; i < N; i += gstr) { degs[i] = 0; degd[i] = 0; cursor[i] = 0; }
    grid.sync();
    for (int e = gtid; e < E; e += gstr) {
        atomicAdd(&degs[src[e]], 1);
        atomicAdd(&degd[dst[e]], 1);
    }
    grid.sync();
    if (blockIdx.x == 0) {
        int tid = threadIdx.x;
        int chunk = (N + 255) / 256;
        int s0 = tid * chunk;
        int s1 = s0 + chunk; if (s1 > N) s1 = N; if (s0 > N) s0 = N;
        int s = 0;
        for (int i = s0; i < s1; ++i) s += degd[i];
        sums[tid] = s;
        __syncthreads();
        for (int off = 1; off < 256; off <<= 1) {
            int v = (tid >= off) ? sums[tid - off] : 0;
            __syncthreads();
            sums[tid] += v;
            __syncthreads();
        }
        int run = sums[tid] - s;
        for (int i = s0; i < s1; ++i) { rowp[i] = run; run += degd[i]; }
        if (tid == 255) rowp[N] = sums[255];
    }
    grid.sync();
    for (int e = gtid; e < E; e += gstr) {
        int s = src[e], d = dst[e];
        int dgs = degs[s], dgd = degs[d];
        float ws_ = (dgs > 0 ? rsqrtf((float)dgs) : 0.f)
                  * (dgd > 0 ? rsqrtf((float)dgd) : 0.f);
        int slot = rowp[d] + atomicAdd(&cursor[d], 1);
        csrs[slot] = s;
        csrw[slot] = ws_;
    }
    grid.sync();
    const float* va = v0;
    float* vb = v1;
    int lane = threadIdx.x & 63;
    int grpbase = lane & 48;
    for (int j = 1; j <= KORD; ++j) {
        if (!flags[j]) break;               // uniform
        float aj = acoef[j];
        for (int idx = gtid; idx < N * 16; idx += gstr) {
            int n = idx >> 4;
            int q = idx & 15;
            int beg = rowp[n], end = rowp[n + 1];
            float4 acc = make_float4(0.f, 0.f, 0.f, 0.f);
            for (int base = beg; base < end; base += 16) {
                int s = 0; float wvv = 0.f;
                int ii = base + q;
                if (ii < end) { s = csrs[ii]; wvv = csrw[ii]; }
                int m = end - base; if (m > 16) m = 16;
                for (int u = 0; u < m; ++u) {
                    int ss = __shfl(s, grpbase + u, 64);
                    float ww = __shfl(wvv, grpbase + u, 64);
                    float4 vv = *(const float4*)(va + ((long)ss << 6) + (q << 2));
                    acc.x += ww * vv.x; acc.y += ww * vv.y;
                    acc.z += ww * vv.z; acc.w += ww * vv.w;
                }
            }
            long o = ((long)n << 6) + (q << 2);
            *(float4*)(vb + o) = acc;
            float4 ov = *(const float4*)(out + o);
            ov.x += aj * acc.x; ov.y += aj * acc.y;
            ov.z += aj * acc.z; ov.w += aj * acc.w;
            *(float4*)(out + o) = ov;
        }
        grid.sync();
        float* tsw = vb; vb = (float*)va; va = tsw;
    }
    for (int idx = gtid; idx < N * 64; idx += gstr) {
        int n = idx >> 6;
        int c = idx & 63;
        float v = out[(long)n * 64 + c];
        float mx = v;
#pragma unroll
        for (int off = 32; off; off >>= 1) mx = fmaxf(mx, __shfl_xor(mx, off, 64));
        float e = expf(v - mx);
        float s = e;
#pragma unroll
        for (int off = 32; off; off >>= 1) s += __shfl_xor(s, off, 64);
        out[(long)n * 64 + c] = v - mx - logf(s);
    }
}

extern "C" void kernel_launch(void* const* d_in, const int* in_sizes, int n_in,
                              void* d_out, int out_size, void* d_ws, size_t ws_size,
                              hipStream_t stream)
{
    const float* x    = (const float*)d_in[0];
    const int*   ei   = (const int*)d_in[1];
    const float* W1   = (const float*)d_in[2];
    const float* b1   = (const float*)d_in[3];
    const float* W2   = (const float*)d_in[4];
    const float* b2   = (const float*)d_in[5];
    const float* temp = (const float*)d_in[6];

    int N = in_sizes[0] / 512;
    int E = in_sizes[1] / 2;
    const int* src = ei;
    const int* dst = ei + E;
    float* out = (float*)d_out;

    char* w = (char*)d_ws;
    auto alloc = [&](size_t bytes) {
        char* p = w;
        w += (bytes + 255) & ~(size_t)255;
        return p;
    };
    float* acoef  = (float*)alloc(64);
    int*   flags  = (int*)alloc(64);
    int*   degs   = (int*)alloc((size_t)N * 4);
    int*   degd   = (int*)alloc((size_t)N * 4);
    int*   cursor = (int*)alloc((size_t)N * 4);
    int*   rowp   = (int*)alloc((size_t)(N + 1) * 4);
    int*   csrs   = (int*)alloc((size_t)E * 4);
    float* csrw   = (float*)alloc((size_t)E * 4);
    ushort* w1b   = (ushort*)alloc(512 * 256 * 2);
    ushort* w2h   = (ushort*)alloc(256 * 64 * 2);
    ushort* w2l   = (ushort*)alloc(256 * 64 * 2);
    float* v0     = (float*)alloc((size_t)N * 64 * 4);
    float* v1     = (float*)alloc((size_t)N * 64 * 4);

    prep_all<<<576, 256, 0, stream>>>(temp, W1, W2, acoef, flags, w1b, w2h, w2l);

    int ntiles = (N + 31) / 32;
    mlp_kernel<<<ntiles, 256, 0, stream>>>(x, w1b, w2h, w2l, b1, b2, v0, out,
                                           acoef, flags, N);

    int Ei = E, Ni = N;
    void* cargs[] = {
        (void*)&src, (void*)&dst, (void*)&Ei, (void*)&Ni,
        (void*)&degs, (void*)&degd, (void*)&cursor, (void*)&rowp,
        (void*)&csrs, (void*)&csrw, (void*)&v0, (void*)&v1, (void*)&out,
        (void*)&acoef, (void*)&flags
    };
    hipLaunchCooperativeKernel((void*)graph_coop, dim3(1024), dim3(256),
                               cargs, 0, stream);
}

// Round 13
// 105.762 us; speedup vs baseline: 1.8949x; 1.8298x over previous
//
#include <hip/hip_runtime.h>
#include <hip/hip_bf16.h>
#include <hip/hip_cooperative_groups.h>
#include <math.h>

// ---------------------------------------------------------------------------
// BernNet: out = log_softmax( bern_prop( relu(x@W1+b1)@W2+b2 ) )
// bern_prop in monomial basis (10 matvecs, not 65); trailing-zero fast path:
// graph work in ONE cooperative kernel that exits when a_j==0 for j>=1
// (log_softmax then fused into the MLP epilogue).
// MLP (R6 structure + 2 fixes): BOTH GEMM1 streams staged via global_load_lds
// (VGPR-free DMA the compiler cannot sink — R7/R9/R11/R12 all proved plain
// loads get serialized); x staged as raw fp32 with SOURCE-side XOR swizzle
// (LDS linear, rule #21) so A ds_read_b128 is conflict-free; fp32->bf16
// conversion on the LDS->reg fragment path. One barrier per K-step.
// h1 kept in LDS (64KB image); phase-2 h1@W2 with split hi/lo bf16 W2;
// fused log_softmax epilogue on the fast path.
// ---------------------------------------------------------------------------

#define KORD 10

namespace cg = cooperative_groups;

typedef __attribute__((ext_vector_type(8))) short bf16x8;
typedef __attribute__((ext_vector_type(4))) float f32x4;

typedef __attribute__((address_space(1))) const unsigned int* gas_t;
typedef __attribute__((address_space(3))) unsigned int* las_t;

static __device__ __forceinline__ void gll16(const void* g, void* l) {
    // per-lane global addr g; wave-uniform LDS base l; writes l + lane*16
    __builtin_amdgcn_global_load_lds((gas_t)g, (las_t)l, 16, 0, 0);
}

static __device__ __forceinline__ ushort f2bf(float f) {   // RNE
    unsigned u = __float_as_uint(f);
    unsigned r = (u + 0x7fffu + ((u >> 16) & 1u)) >> 16;
    return (ushort)r;
}
static __device__ __forceinline__ float bf2f(ushort h) {
    return __uint_as_float(((unsigned)h) << 16);
}
// truncation pack: low16 = bf16_trunc(a), high16 = bf16_trunc(b)
static __device__ __forceinline__ uint pk2t(float a, float b) {
    return (__float_as_uint(a) >> 16) | (__float_as_uint(b) & 0xffff0000u);
}
static __device__ __forceinline__ bf16x8 mk8(uint a, uint b, uint c, uint d) {
    union { uint4 u; bf16x8 v; } x;
    x.u = make_uint4(a, b, c, d);
    return x.v;
}

// ---- one-time setup: monomial coeffs + weight conversion -------------------
// W1 -> fragment-linear bf16: idx = kt*8192 + col*32 + lg*8 + j  (k=kt*32+lg*8+j)
// W2 -> hi/lo bf16:           idx = ks*2048 + col*32 + lg*8 + j  (k=ks*32+lg*8+j)
__global__ void prep_all(const float* __restrict__ temp,
                         const float* __restrict__ W1, const float* __restrict__ W2,
                         float* __restrict__ acoef, int* __restrict__ flags,
                         ushort* __restrict__ w1b,
                         ushort* __restrict__ w2h, ushort* __restrict__ w2l)
{
    int tid = blockIdx.x * 256 + threadIdx.x;
    if (tid == 0) {
        int C[KORD + 1][KORD + 1];
        for (int n = 0; n <= KORD; ++n) {
            for (int k = 0; k <= KORD; ++k) C[n][k] = 0;
            C[n][0] = 1;
            for (int k = 1; k <= n; ++k)
                C[n][k] = C[n - 1][k - 1] + ((k <= n - 1) ? C[n - 1][k] : 0);
        }
        float a[KORD + 1];
        for (int j = 0; j <= KORD; ++j) a[j] = 0.f;
        for (int m = 0; m <= KORD; ++m) {
            float tm = temp[m];
            tm = tm > 0.f ? tm : 0.f;
            float cm = (float)C[KORD][m] / 1024.0f;
            for (int p = 0; p <= m; ++p)
                for (int q = 0; q <= KORD - m; ++q) {
                    int Mij = ((p & 1) ? -1 : 1) * C[m][p] * C[KORD - m][q];
                    a[p + q] += cm * tm * (float)Mij;
                }
        }
        for (int j = 0; j <= KORD; ++j) acoef[j] = a[j];
        int any = 0;
        for (int j = KORD; j >= 0; --j) {
            if (a[j] != 0.f) any = 1;
            flags[j] = any;
        }
    }
    if (tid < 512 * 256) {
        int j = tid & 7, lg = (tid >> 3) & 3, col = (tid >> 5) & 255, kt = tid >> 13;
        int k = kt * 32 + lg * 8 + j;
        w1b[tid] = f2bf(W1[k * 256 + col]);
    } else if (tid < 512 * 256 + 256 * 64) {
        int t2 = tid - 512 * 256;
        int j = t2 & 7, lg = (t2 >> 3) & 3, col = (t2 >> 5) & 63, ks = t2 >> 11;
        int k = ks * 32 + lg * 8 + j;
        float v = W2[k * 64 + col];
        ushort hi = f2bf(v);
        ushort lo = f2bf(v - bf2f(hi));
        w2h[t2] = hi; w2l[t2] = lo;
    }
}

// ---- fused MLP ------------------------------------------------------------
// 512 thr / 8 waves; tile 128 rows x 256 cols, K=512, BK=32.
// LDS: [0:16K) A0 fp32, [16K:32K) A1, [32K:48K) B0 bf16, [48K:64K) B1;
// h1 image reuses [0:64K). Wave (wm=wid>>2, wn=wid&3) -> 64x64 output.
// A LDS layout: row-major [128 rows][128B], 16B-unit kq pre-swizzled at the
// GLOBAL source: position kq holds floats (kq ^ ((row&3)<<1))*4 .. +3.
__global__ __launch_bounds__(512, 4) void mlp_kernel(
    const float* __restrict__ x,
    const ushort* __restrict__ w1b,
    const ushort* __restrict__ w2h, const ushort* __restrict__ w2l,
    const float* __restrict__ b1, const float* __restrict__ b2,
    float* __restrict__ v0, float* __restrict__ out,
    const float* __restrict__ acoef, const int* __restrict__ flags, int N)
{
    __shared__ __align__(16) char sm[65536];

    const int t    = threadIdx.x;
    const int lane = t & 63;
    const int wid  = t >> 6;        // 0..7
    const int wm   = wid >> 2;      // 0..1 row half (64 rows)
    const int wn   = wid & 3;       // 0..3 col quarter (64 cols)
    const int l15  = lane & 15;
    const int lg   = lane >> 4;
    const int row0 = blockIdx.x * 128;
    const int wlds = (t >> 6) << 10;        // this wave's 1KB slice in a set

    // staging geometry (per thread): A slot row = t>>3, kq = t&7
    const int srow = t >> 3;
    const int skq  = t & 7;
    const int ssw  = (srow & 3) << 1;
    int gr0 = row0 + srow;      if (gr0 > N - 1) gr0 = N - 1;
    int gr1 = row0 + srow + 64; if (gr1 > N - 1) gr1 = N - 1;
    const float* gs0 = x + (size_t)gr0 * 512 + ((skq ^ ssw) << 2);
    const float* gs1 = x + (size_t)gr1 * 512 + ((skq ^ ssw) << 2);
    const char* w1g = (const char*)w1b;

    f32x4 acc[4][4];
#pragma unroll
    for (int i = 0; i < 4; ++i)
#pragma unroll
        for (int j = 0; j < 4; ++j) acc[i][j] = (f32x4)0.f;

    // ---- prologue: stage kt=0 into buf0 ----
    gll16(gs0,                 sm + wlds);
    gll16(gs1,                 sm + 8192 + wlds);
    gll16(w1g + t * 16,        sm + 32768 + wlds);
    gll16(w1g + 8192 + t * 16, sm + 40960 + wlds);
    __syncthreads();

#pragma unroll 2
    for (int kt = 0; kt < 16; ++kt) {
        // issue next K-step's staging (DMA, no VGPRs -> cannot be sunk)
        if (kt < 15) {
            int ktn = kt + 1;
            char* An = sm + (ktn & 1) * 16384;
            char* Bn = sm + 32768 + (ktn & 1) * 16384;
            gll16(gs0 + ktn * 32,                       An + wlds);
            gll16(gs1 + ktn * 32,                       An + 8192 + wlds);
            gll16(w1g + ktn * 16384 + t * 16,           Bn + wlds);
            gll16(w1g + ktn * 16384 + 8192 + t * 16,    Bn + 8192 + wlds);
        }
        // compute from current buffers
        const char* Ac = sm + (kt & 1) * 16384;
        const char* Bc = sm + 32768 + (kt & 1) * 16384;
        bf16x8 Af[4];
#pragma unroll
        for (int mf = 0; mf < 4; ++mf) {
            int rowIdx = wm * 64 + mf * 16 + l15;
            int sw = (rowIdx & 3) << 1;
            const char* pa = Ac + rowIdx * 128 + (((2 * lg) ^ sw) << 4);
            float4 fa = *(const float4*)pa;
            float4 fb = *(const float4*)(pa + 16);
            Af[mf] = mk8(pk2t(fa.x, fa.y), pk2t(fa.z, fa.w),
                         pk2t(fb.x, fb.y), pk2t(fb.z, fb.w));
        }
#pragma unroll
        for (int nf = 0; nf < 4; ++nf) {
            bf16x8 B = *(const bf16x8*)(Bc + (wn * 64 + nf * 16 + l15) * 64 + lg * 16);
#pragma unroll
            for (int mf = 0; mf < 4; ++mf)
                acc[mf][nf] = __builtin_amdgcn_mfma_f32_16x16x32_bf16(Af[mf], B, acc[mf][nf], 0, 0, 0);
        }
        __syncthreads();        // drains next-step DMA; buffers swap safely
    }

    // ---- h1 = relu(acc+b1) -> bf16 -> LDS frag-linear image [0:64K) ----
    ushort* h1l = (ushort*)sm;
#pragma unroll
    for (int nf = 0; nf < 4; ++nf) {
        int col = wn * 64 + nf * 16 + l15;
        float bb = b1[col];
        int ks = col >> 5, lgw = (col >> 3) & 3, j = col & 7;
#pragma unroll
        for (int mf = 0; mf < 4; ++mf) {
            int g = wm * 4 + mf;
#pragma unroll
            for (int r = 0; r < 4; ++r) {
                float v = fmaxf(acc[mf][nf][r] + bb, 0.f);
                int l15w = lg * 4 + r;
                h1l[(((ks * 8 + g) * 64) + l15w * 4 + lgw) * 8 + j] = f2bf(v);
            }
        }
    }
    __syncthreads();

    // ---- phase 2: wave wid -> rows wid*16..+15, all 64 cols, K=256 ----
    f32x4 acc2[4];
#pragma unroll
    for (int i = 0; i < 4; ++i) acc2[i] = (f32x4)0.f;
#pragma unroll
    for (int ks = 0; ks < 8; ++ks) {
        bf16x8 A = *(const bf16x8*)&h1l[((ks * 8 + wid) * 64 + l15 * 4 + lg) * 8];
#pragma unroll
        for (int nf = 0; nf < 4; ++nf) {
            size_t bo = (size_t)ks * 2048 + (nf * 16 + l15) * 32 + (lg << 3);
            bf16x8 Bh = *(const bf16x8*)(w2h + bo);
            bf16x8 Bl = *(const bf16x8*)(w2l + bo);
            acc2[nf] = __builtin_amdgcn_mfma_f32_16x16x32_bf16(A, Bh, acc2[nf], 0, 0, 0);
            acc2[nf] = __builtin_amdgcn_mfma_f32_16x16x32_bf16(A, Bl, acc2[nf], 0, 0, 0);
        }
    }

    // ---- epilogue ----
    int flag1 = flags[1];
    float a0c = acoef[0];
    float z[4][4];
#pragma unroll
    for (int nf = 0; nf < 4; ++nf) {
        float bb = b2[nf * 16 + l15];
#pragma unroll
        for (int r = 0; r < 4; ++r) z[nf][r] = acc2[nf][r] + bb;
    }
    if (!flag1) {
        // fused log_softmax: the 16 l15-lanes of this lg group share 4 rows
#pragma unroll
        for (int r = 0; r < 4; ++r) {
            int row = row0 + wid * 16 + lg * 4 + r;
            float mx = fmaxf(fmaxf(z[0][r], z[1][r]), fmaxf(z[2][r], z[3][r]));
#pragma unroll
            for (int off = 1; off < 16; off <<= 1) mx = fmaxf(mx, __shfl_xor(mx, off, 64));
            float s = expf(z[0][r] - mx) + expf(z[1][r] - mx)
                    + expf(z[2][r] - mx) + expf(z[3][r] - mx);
#pragma unroll
            for (int off = 1; off < 16; off <<= 1) s += __shfl_xor(s, off, 64);
            float lns = logf(s);
            if (row < N) {
#pragma unroll
                for (int nf = 0; nf < 4; ++nf)
                    out[(size_t)row * 64 + nf * 16 + l15] = z[nf][r] - mx - lns;
            }
        }
    } else {
#pragma unroll
        for (int nf = 0; nf < 4; ++nf) {
            int col = nf * 16 + l15;
#pragma unroll
            for (int r = 0; r < 4; ++r) {
                int row = row0 + wid * 16 + lg * 4 + r;
                if (row < N) {
                    size_t o = (size_t)row * 64 + col;
                    v0[o] = z[nf][r];
                    out[o] = a0c * z[nf][r];
                }
            }
        }
    }
}

// ---- all graph work in one cooperative kernel (active path only) ----------
__global__ __launch_bounds__(256) void graph_coop(
    const int* __restrict__ src, const int* __restrict__ dst, int E, int N,
    int* __restrict__ degs, int* __restrict__ degd, int* __restrict__ cursor,
    int* __restrict__ rowp, int* __restrict__ csrs, float* __restrict__ csrw,
    float* __restrict__ v0, float* __restrict__ v1, float* __restrict__ out,
    const float* __restrict__ acoef, const int* __restrict__ flags)
{
    __shared__ int sums[256];
    if (!flags[1]) return;                  // uniform early-out: no syncs occur
    cg::grid_group grid = cg::this_grid();
    int gtid = blockIdx.x * 256 + threadIdx.x;
    int gstr = gridDim.x * 256;

    for (int i = gtid; i < N; i += gstr) { degs[i] = 0; degd[i] = 0; cursor[i] = 0; }
    grid.sync();
    for (int e = gtid; e < E; e += gstr) {
        atomicAdd(&degs[src[e]], 1);
        atomicAdd(&degd[dst[e]], 1);
    }
    grid.sync();
    if (blockIdx.x == 0) {
        int tid = threadIdx.x;
        int chunk = (N + 255) / 256;
        int s0 = tid * chunk;
        int s1 = s0 + chunk; if (s1 > N) s1 = N; if (s0 > N) s0 = N;
        int s = 0;
        for (int i = s0; i < s1; ++i) s += degd[i];
        sums[tid] = s;
        __syncthreads();
        for (int off = 1; off < 256; off <<= 1) {
            int v = (tid >= off) ? sums[tid - off] : 0;
            __syncthreads();
            sums[tid] += v;
            __syncthreads();
        }
        int run = sums[tid] - s;
        for (int i = s0; i < s1; ++i) { rowp[i] = run; run += degd[i]; }
        if (tid == 255) rowp[N] = sums[255];
    }
    grid.sync();
    for (int e = gtid; e < E; e += gstr) {
        int s = src[e], d = dst[e];
        int dgs = degs[s], dgd = degs[d];
        float ws_ = (dgs > 0 ? rsqrtf((float)dgs) : 0.f)
                  * (dgd > 0 ? rsqrtf((float)dgd) : 0.f);
        int slot = rowp[d] + atomicAdd(&cursor[d], 1);
        csrs[slot] = s;
        csrw[slot] = ws_;
    }
    grid.sync();
    const float* va = v0;
    float* vb = v1;
    int lane = threadIdx.x & 63;
    int grpbase = lane & 48;
    for (int j = 1; j <= KORD; ++j) {
        if (!flags[j]) break;               // uniform
        float aj = acoef[j];
        for (int idx = gtid; idx < N * 16; idx += gstr) {
            int n = idx >> 4;
            int q = idx & 15;
            int beg = rowp[n], end = rowp[n + 1];
            float4 acc = make_float4(0.f, 0.f, 0.f, 0.f);
            for (int base = beg; base < end; base += 16) {
                int s = 0; float wvv = 0.f;
                int ii = base + q;
                if (ii < end) { s = csrs[ii]; wvv = csrw[ii]; }
                int m = end - base; if (m > 16) m = 16;
                for (int u = 0; u < m; ++u) {
                    int ss = __shfl(s, grpbase + u, 64);
                    float ww = __shfl(wvv, grpbase + u, 64);
                    float4 vv = *(const float4*)(va + ((long)ss << 6) + (q << 2));
                    acc.x += ww * vv.x; acc.y += ww * vv.y;
                    acc.z += ww * vv.z; acc.w += ww * vv.w;
                }
            }
            long o = ((long)n << 6) + (q << 2);
            *(float4*)(vb + o) = acc;
            float4 ov = *(const float4*)(out + o);
            ov.x += aj * acc.x; ov.y += aj * acc.y;
            ov.z += aj * acc.z; ov.w += aj * acc.w;
            *(float4*)(out + o) = ov;
        }
        grid.sync();
        float* tsw = vb; vb = (float*)va; va = tsw;
    }
    for (int idx = gtid; idx < N * 64; idx += gstr) {
        int n = idx >> 6;
        int c = idx & 63;
        float v = out[(long)n * 64 + c];
        float mx = v;
#pragma unroll
        for (int off = 32; off; off >>= 1) mx = fmaxf(mx, __shfl_xor(mx, off, 64));
        float e = expf(v - mx);
        float s = e;
#pragma unroll
        for (int off = 32; off; off >>= 1) s += __shfl_xor(s, off, 64);
        out[(long)n * 64 + c] = v - mx - logf(s);
    }
}

extern "C" void kernel_launch(void* const* d_in, const int* in_sizes, int n_in,
                              void* d_out, int out_size, void* d_ws, size_t ws_size,
                              hipStream_t stream)
{
    const float* x    = (const float*)d_in[0];
    const int*   ei   = (const int*)d_in[1];
    const float* W1   = (const float*)d_in[2];
    const float* b1   = (const float*)d_in[3];
    const float* W2   = (const float*)d_in[4];
    const float* b2   = (const float*)d_in[5];
    const float* temp = (const float*)d_in[6];

    int N = in_sizes[0] / 512;
    int E = in_sizes[1] / 2;
    const int* src = ei;
    const int* dst = ei + E;
    float* out = (float*)d_out;

    char* w = (char*)d_ws;
    auto alloc = [&](size_t bytes) {
        char* p = w;
        w += (bytes + 255) & ~(size_t)255;
        return p;
    };
    float* acoef  = (float*)alloc(64);
    int*   flags  = (int*)alloc(64);
    int*   degs   = (int*)alloc((size_t)N * 4);
    int*   degd   = (int*)alloc((size_t)N * 4);
    int*   cursor = (int*)alloc((size_t)N * 4);
    int*   rowp   = (int*)alloc((size_t)(N + 1) * 4);
    int*   csrs   = (int*)alloc((size_t)E * 4);
    float* csrw   = (float*)alloc((size_t)E * 4);
    ushort* w1b   = (ushort*)alloc(512 * 256 * 2);
    ushort* w2h   = (ushort*)alloc(256 * 64 * 2);
    ushort* w2l   = (ushort*)alloc(256 * 64 * 2);
    float* v0     = (float*)alloc((size_t)N * 64 * 4);
    float* v1     = (float*)alloc((size_t)N * 64 * 4);

    prep_all<<<576, 256, 0, stream>>>(temp, W1, W2, acoef, flags, w1b, w2h, w2l);

    int ntiles = (N + 127) / 128;
    mlp_kernel<<<ntiles, 512, 0, stream>>>(x, w1b, w2h, w2l, b1, b2, v0, out,
                                           acoef, flags, N);

    int Ei = E, Ni = N;
    void* cargs[] = {
        (void*)&src, (void*)&dst, (void*)&Ei, (void*)&Ni,
        (void*)&degs, (void*)&degd, (void*)&cursor, (void*)&rowp,
        (void*)&csrs, (void*)&csrw, (void*)&v0, (void*)&v1, (void*)&out,
        (void*)&acoef, (void*)&flags
    };
    hipLaunchCooperativeKernel((void*)graph_coop, dim3(1024), dim3(256),
                               cargs, 0, stream);
}